// Round 6
// baseline (16536.143 us; speedup 1.0000x reference)
//
#include <hip/hip_runtime.h>
#include <stdint.h>

#define L_SEQ 4096
#define E_DIM 512
#define H_DIM 512
#define G_DIM 2048   // 4*H
#define NTAG  32

typedef unsigned long long u64;
typedef unsigned short     u16;
typedef unsigned char      u8;
typedef __attribute__((ext_vector_type(4))) unsigned int uint4v;

__device__ __forceinline__ float bf2f(u16 u) {
    union { unsigned int i; float f; } v; v.i = ((unsigned int)u) << 16; return v.f;
}
// dtype sniff: trans[START][0..1] both exactly -10000.0.
// bf16: u16[0]==u16[1]==0xC61C. f32 (bits 0xC61C4000): u16[0]=0x4000 != u16[1].
__device__ __forceinline__ bool sniff_f32(const void* trans_raw) {
    const u16* p = (const u16*)trans_raw;
    return p[0] != p[1];
}
__device__ __forceinline__ float ldf(const void* base, long idx, bool isf32) {
    if (isf32) return ((const float*)base)[idx];
    return bf2f(((const u16*)base)[idx]);
}
__device__ __forceinline__ void unpack8_bf16(const u16* src, float* dst) {
    uint4 p = *(const uint4*)src;
    dst[0] = __uint_as_float(p.x << 16); dst[1] = __uint_as_float(p.x & 0xffff0000u);
    dst[2] = __uint_as_float(p.y << 16); dst[3] = __uint_as_float(p.y & 0xffff0000u);
    dst[4] = __uint_as_float(p.z << 16); dst[5] = __uint_as_float(p.z & 0xffff0000u);
    dst[6] = __uint_as_float(p.w << 16); dst[7] = __uint_as_float(p.w & 0xffff0000u);
}

// fast activations: v_exp_f32 (2^x) + v_rcp_f32. Saturate cleanly at +-inf.
#define LOG2E 1.44269504088896340736f
__device__ __forceinline__ float fsig(float x) {
    return __builtin_amdgcn_rcpf(1.f + __builtin_amdgcn_exp2f(-x * LOG2E));
}
__device__ __forceinline__ float ftanh(float x) {
    return 1.f - 2.f * __builtin_amdgcn_rcpf(1.f + __builtin_amdgcn_exp2f(x * (2.f * LOG2E)));
}

// ---------------------------------------------------------------------------
// K1 (VALU): xp = gather(embed,sent) @ w_ih^T + (b_ih+b_hh). Grid (256, 2).
// ---------------------------------------------------------------------------
__global__ __launch_bounds__(256) void k_xproj(
    const int* __restrict__ sent, const void* __restrict__ embed,
    const void* __restrict__ w_ih_f, const void* __restrict__ b_ih_f, const void* __restrict__ b_hh_f,
    const void* __restrict__ w_ih_b, const void* __restrict__ b_ih_b, const void* __restrict__ b_hh_b,
    const void* __restrict__ trans_raw,
    float* __restrict__ xp_f, float* __restrict__ xp_b)
{
    const bool isf32 = sniff_f32(trans_raw);
    const int dir = (int)blockIdx.y;
    const void* W  = dir ? w_ih_b : w_ih_f;
    const void* bi = dir ? b_ih_b : b_ih_f;
    const void* bh = dir ? b_hh_b : b_hh_f;
    float* xp = dir ? xp_b : xp_f;
    const int m0 = (int)blockIdx.x * 16;
    const int tid = (int)threadIdx.x;

    __shared__ float xs[16][520];
    __shared__ float wl[16][520];

    {
        const int r = tid >> 4, c0 = (tid & 15) * 32;
        const long row = sent[m0 + r];
        if (isf32) {
            const float* src = (const float*)embed + row * E_DIM + c0;
            #pragma unroll
            for (int i = 0; i < 32; i += 4) *(float4*)&xs[r][c0 + i] = *(const float4*)(src + i);
        } else {
            const u16* src = (const u16*)embed + row * E_DIM + c0;
            #pragma unroll
            for (int i = 0; i < 32; i += 8) unpack8_bf16(src + i, &xs[r][c0 + i]);
        }
    }
    __syncthreads();

    const int mi = tid >> 4, gi = tid & 15;
    for (int gb = 0; gb < 128; ++gb) {
        const int g0 = gb * 16;
        {
            const int r = tid >> 4, c0 = (tid & 15) * 32;
            if (isf32) {
                const float* src = (const float*)W + (long)(g0 + r) * E_DIM + c0;
                #pragma unroll
                for (int i = 0; i < 32; i += 4) *(float4*)&wl[r][c0 + i] = *(const float4*)(src + i);
            } else {
                const u16* src = (const u16*)W + (long)(g0 + r) * E_DIM + c0;
                #pragma unroll
                for (int i = 0; i < 32; i += 8) unpack8_bf16(src + i, &wl[r][c0 + i]);
            }
        }
        __syncthreads();

        float acc = 0.f;
        #pragma unroll 4
        for (int k = 0; k < E_DIM; k += 4) {
            const float4 xv = *(const float4*)&xs[mi][k];
            const float4 wv = *(const float4*)&wl[gi][k];
            acc = fmaf(xv.x, wv.x, acc); acc = fmaf(xv.y, wv.y, acc);
            acc = fmaf(xv.z, wv.z, acc); acc = fmaf(xv.w, wv.w, acc);
        }
        const int g = g0 + gi;
        const float bias = ldf(bi, g, isf32) + ldf(bh, g, isf32);
        xp[(long)(m0 + mi) * G_DIM + g] = acc + bias;
        __syncthreads();
    }
}

// ---------------------------------------------------------------------------
// K2: persistent BiLSTM. Grid 256 blocks; live ones are blk%8<2:
//   blk%8==0 -> forward chain (32 WGs, all on XCD0 under round-robin),
//   blk%8==1 -> backward chain (XCD1). wg = blk>>3, 16 dims each.
// Exchange: tagged u64 {step,f32} per dim. Producers: relaxed agent atomic
// store (write-through; visits the shared same-XCD L2 en route to LLC).
// Consumers: 62 pollers x 8 words via sc0 dwordx4 (L2-visible) with sticky
// fallback to agent-atomic polling -> correct under ANY placement (G16).
// ---------------------------------------------------------------------------
__global__ __launch_bounds__(256, 1) void k_lstm(
    const void* __restrict__ w_hh_f, const void* __restrict__ w_hh_b,
    const void* __restrict__ h0, const void* __restrict__ c0,
    const void* __restrict__ trans_raw,
    const float* __restrict__ xp_f, const float* __restrict__ xp_b,
    u64* __restrict__ hsT_f, u64* __restrict__ hsT_b)
{
    const int blk = (int)blockIdx.x;
    if ((blk & 7) >= 2) return;          // 64 live WGs out of 256 dispatched
    const bool isf32 = sniff_f32(trans_raw);
    const int dir = blk & 7;             // 0 fwd, 1 bwd
    const int wg  = blk >> 3;            // 0..31
    const int j0  = wg * 16;
    const void* Whh = dir ? w_hh_b : w_hh_f;
    const float* xp = dir ? xp_b : xp_f;
    u64* hsT        = dir ? hsT_b : hsT_f;

    const int tid = (int)threadIdx.x;
    const int rp  = tid >> 3;      // row-pair 0..31
    const int ks  = tid & 7;       // k-segment (64 wide)
    const int d   = rp >> 1;       // local dim 0..15
    const int gp  = rp & 1;        // 0 -> gates i,f ; 1 -> gates g,o
    const int g0r = gp * 2;

    __shared__ float h_lds[512 + 32];   // p(j) = j + ((j>>6)<<2)

    // 2 rows x 64 k of W_hh per lane, f32
    float wreg[2][64];
    #pragma unroll
    for (int rl = 0; rl < 2; ++rl) {
        const long roff = (long)((g0r + rl) * H_DIM + j0 + d) * H_DIM + ks * 64;
        if (isf32) {
            const float* wrow = (const float*)Whh + roff;
            #pragma unroll
            for (int b = 0; b < 16; ++b) *(float4*)&wreg[rl][b * 4] = *(const float4*)(wrow + b * 4);
        } else {
            const u16* wrow = (const u16*)Whh + roff;
            #pragma unroll
            for (int b = 0; b < 8; ++b) unpack8_bf16(wrow + b * 8, &wreg[rl][b * 8]);
        }
    }

    {   // init h_lds (w0 even: never straddles a 64-block)
        const int w0 = tid * 2;
        h_lds[w0 + ((w0 >> 6) << 2)]     = ldf(h0, dir * H_DIM + w0, isf32);
        h_lds[w0 + 1 + ((w0 >> 6) << 2)] = ldf(h0, dir * H_DIM + w0 + 1, isf32);
    }

    const bool is_act = ((tid & 15) == 0);   // 16 act lanes: tid = 16*d
    const int  jown   = j0 + d;
    float cst = 0.f;
    if (is_act) cst = ldf(c0, dir * H_DIM + jown, isf32);

    // pollers: lanes tid = 4c+1 (c=0..61), chunk c = remote words [8c, 8c+8)
    // after skipping own 16-word slice (8-aligned chunks never straddle it).
    const int c = ((tid & 3) == 1) ? (tid >> 2) : -1;
    int jw = -1;
    if (c >= 0 && c < 62) { const int w = c * 8; jw = w + (w >= j0 ? 16 : 0); }
    int fastmode = 1;                    // sticky per-lane fast/slow decision

    int t = dir ? (L_SEQ - 1) : 0;
    float xc0 = 0, xc1 = 0, xc2 = 0, xc3 = 0, xn0 = 0, xn1 = 0, xn2 = 0, xn3 = 0;
    if (is_act) {
        const float* xr = xp + (long)t * G_DIM + jown;
        xn0 = xr[0]; xn1 = xr[H_DIM]; xn2 = xr[2 * H_DIM]; xn3 = xr[3 * H_DIM];
    }
    __syncthreads();

    #pragma unroll 1
    for (int k = 0; k < L_SEQ; ++k) {
        t = dir ? (L_SEQ - 1 - k) : k;
        if (is_act) {
            xc0 = xn0; xc1 = xn1; xc2 = xn2; xc3 = xn3;
            if (k + 1 < L_SEQ) {
                const int nt = dir ? (t - 1) : (t + 1);
                const float* xr = xp + (long)nt * G_DIM + jown;
                xn0 = xr[0]; xn1 = xr[H_DIM]; xn2 = xr[2 * H_DIM]; xn3 = xr[3 * H_DIM];
            }
        }

        // matvec: 2 rows x 64 k
        float a0 = 0, a1 = 0;
        const float4* hb = (const float4*)(h_lds + ks * 68);
        #pragma unroll
        for (int q = 0; q < 16; ++q) {
            const float4 hv = hb[q];
            a0 = fmaf(wreg[0][4*q+0], hv.x, a0); a0 = fmaf(wreg[0][4*q+1], hv.y, a0);
            a0 = fmaf(wreg[0][4*q+2], hv.z, a0); a0 = fmaf(wreg[0][4*q+3], hv.w, a0);
            a1 = fmaf(wreg[1][4*q+0], hv.x, a1); a1 = fmaf(wreg[1][4*q+1], hv.y, a1);
            a1 = fmaf(wreg[1][4*q+2], hv.z, a1); a1 = fmaf(wreg[1][4*q+3], hv.w, a1);
        }
        #pragma unroll
        for (int m = 1; m < 8; m <<= 1) { a0 += __shfl_xor(a0, m); a1 += __shfl_xor(a1, m); }
        const float b0 = __shfl_xor(a0, 8);
        const float b1 = __shfl_xor(a1, 8);

        if (is_act) {
            const float iv = fsig(a0 + xc0);
            const float fo = fsig(a1 + xc1);
            const float gv = ftanh(b0 + xc2);
            const float ov = fsig(b1 + xc3);
            cst = fo * cst + iv * gv;
            const float hv2 = ov * ftanh(cst);
            h_lds[jown + ((jown >> 6) << 2)] = hv2;
            const u64 pk = (((u64)(unsigned)(k + 1)) << 32) | (u64)__float_as_uint(hv2);
            __hip_atomic_store(&hsT[(long)t * H_DIM + jown], pk,
                               __ATOMIC_RELAXED, __HIP_MEMORY_SCOPE_AGENT);
        }

        if (k + 1 < L_SEQ && jw >= 0) {
            const unsigned tagv = (unsigned)(k + 1);
            u64* pw = &hsT[(long)t * H_DIM + jw];   // 64B-aligned, 8 words
            uint4v A = {0,0,0,0}, B = {0,0,0,0}, C = {0,0,0,0}, D = {0,0,0,0};
            bool g0 = false, g1 = false, g2 = false, g3 = false;
            if (fastmode) {
                #pragma unroll 1
                for (int r = 0; r < 64; ++r) {
                    if (!g0) asm volatile("global_load_dwordx4 %0, %1, off sc0" : "=v"(A) : "v"(pw));
                    if (!g1) asm volatile("global_load_dwordx4 %0, %1, off sc0" : "=v"(B) : "v"(pw + 2));
                    if (!g2) asm volatile("global_load_dwordx4 %0, %1, off sc0" : "=v"(C) : "v"(pw + 4));
                    if (!g3) asm volatile("global_load_dwordx4 %0, %1, off sc0" : "=v"(D) : "v"(pw + 6));
                    asm volatile("s_waitcnt vmcnt(0)" : "+v"(A), "+v"(B), "+v"(C), "+v"(D));
                    g0 = g0 || (A.y == tagv && A.w == tagv);
                    g1 = g1 || (B.y == tagv && B.w == tagv);
                    g2 = g2 || (C.y == tagv && C.w == tagv);
                    g3 = g3 || (D.y == tagv && D.w == tagv);
                    if (g0 && g1 && g2 && g3) break;
                }
                if (!(g0 && g1 && g2 && g3)) fastmode = 0;   // sticky fallback
            }
            if (!g0) { u64 v;
                do { v = __hip_atomic_load(pw + 0, __ATOMIC_RELAXED, __HIP_MEMORY_SCOPE_AGENT); } while ((unsigned)(v >> 32) != tagv);
                A.x = (unsigned)v;
                do { v = __hip_atomic_load(pw + 1, __ATOMIC_RELAXED, __HIP_MEMORY_SCOPE_AGENT); } while ((unsigned)(v >> 32) != tagv);
                A.z = (unsigned)v; }
            if (!g1) { u64 v;
                do { v = __hip_atomic_load(pw + 2, __ATOMIC_RELAXED, __HIP_MEMORY_SCOPE_AGENT); } while ((unsigned)(v >> 32) != tagv);
                B.x = (unsigned)v;
                do { v = __hip_atomic_load(pw + 3, __ATOMIC_RELAXED, __HIP_MEMORY_SCOPE_AGENT); } while ((unsigned)(v >> 32) != tagv);
                B.z = (unsigned)v; }
            if (!g2) { u64 v;
                do { v = __hip_atomic_load(pw + 4, __ATOMIC_RELAXED, __HIP_MEMORY_SCOPE_AGENT); } while ((unsigned)(v >> 32) != tagv);
                C.x = (unsigned)v;
                do { v = __hip_atomic_load(pw + 5, __ATOMIC_RELAXED, __HIP_MEMORY_SCOPE_AGENT); } while ((unsigned)(v >> 32) != tagv);
                C.z = (unsigned)v; }
            if (!g3) { u64 v;
                do { v = __hip_atomic_load(pw + 6, __ATOMIC_RELAXED, __HIP_MEMORY_SCOPE_AGENT); } while ((unsigned)(v >> 32) != tagv);
                D.x = (unsigned)v;
                do { v = __hip_atomic_load(pw + 7, __ATOMIC_RELAXED, __HIP_MEMORY_SCOPE_AGENT); } while ((unsigned)(v >> 32) != tagv);
                D.z = (unsigned)v; }
            // 8 consecutive floats; chunk stays inside one 64-block -> 2 b128s
            const int d0 = jw + ((jw >> 6) << 2);
            float4 lo, hi;
            lo.x = __uint_as_float(A.x); lo.y = __uint_as_float(A.z);
            lo.z = __uint_as_float(B.x); lo.w = __uint_as_float(B.z);
            hi.x = __uint_as_float(C.x); hi.y = __uint_as_float(C.z);
            hi.z = __uint_as_float(D.x); hi.w = __uint_as_float(D.z);
            *(float4*)&h_lds[d0]     = lo;
            *(float4*)&h_lds[d0 + 4] = hi;
        }
        __syncthreads();
    }
}

// ---------------------------------------------------------------------------
// K3: feats[t][n] = hs_f[t]·w_out[n][:512] + hs_b[t]·w_out[n][512:] + b_out[n]
// hsT: tagged u64, f32 payload in low word (even float index).
// ---------------------------------------------------------------------------
__global__ __launch_bounds__(256) void k_feats(
    const u64* __restrict__ hsT_f, const u64* __restrict__ hsT_b,
    const void* __restrict__ w_out, const void* __restrict__ b_out,
    const void* __restrict__ trans_raw, float* __restrict__ feats)
{
    const bool isf32 = sniff_f32(trans_raw);
    const int n  = (int)threadIdx.x & 31;
    const int tl = (int)threadIdx.x >> 5;
    const int t  = (int)blockIdx.x * 8 + tl;
    const float* hf  = (const float*)(hsT_f + (long)t * H_DIM);
    const float* hbp = (const float*)(hsT_b + (long)t * H_DIM);
    float acc = ldf(b_out, n, isf32);
    if (isf32) {
        const float* wf = (const float*)w_out + (long)n * 1024;
        const float* wb = wf + 512;
        #pragma unroll 4
        for (int j2 = 0; j2 < 256; ++j2) {
            acc = fmaf(hf [4 * j2],     wf[2 * j2],     acc);
            acc = fmaf(hf [4 * j2 + 2], wf[2 * j2 + 1], acc);
            acc = fmaf(hbp[4 * j2],     wb[2 * j2],     acc);
            acc = fmaf(hbp[4 * j2 + 2], wb[2 * j2 + 1], acc);
        }
    } else {
        const unsigned int* wf = (const unsigned int*)((const u16*)w_out + (long)n * 1024);
        const unsigned int* wb = (const unsigned int*)((const u16*)w_out + (long)n * 1024 + 512);
        #pragma unroll 4
        for (int j2 = 0; j2 < 256; ++j2) {
            const unsigned int wp = wf[j2];
            const unsigned int wq = wb[j2];
            acc = fmaf(hf [4 * j2],     __uint_as_float(wp << 16),         acc);
            acc = fmaf(hf [4 * j2 + 2], __uint_as_float(wp & 0xffff0000u), acc);
            acc = fmaf(hbp[4 * j2],     __uint_as_float(wq << 16),         acc);
            acc = fmaf(hbp[4 * j2 + 2], __uint_as_float(wq & 0xffff0000u), acc);
        }
    }
    feats[(long)t * 32 + n] = acc;
}

// ---------------------------------------------------------------------------
// K4: Viterbi forward, register fv + shfl, 4-deep feats prefetch ring
// (static indices via 4x unroll), then chunked parallel backtrace.
// Output (f32): out[0]=score, out[1..4096]=path tags.
// ---------------------------------------------------------------------------
__global__ __launch_bounds__(64) void k_viterbi(
    const float* __restrict__ feats, const void* __restrict__ trans_raw,
    u8* __restrict__ bptr, float* __restrict__ out)
{
    const bool isf32 = sniff_f32(trans_raw);
    const int lane = (int)threadIdx.x;
    const int n = lane & 31, half = lane >> 5;
    __shared__ u8 mlds[64 * 32];
    __shared__ u8 entry[64];

    float tr[16];
    #pragma unroll
    for (int i = 0; i < 16; ++i) tr[i] = ldf(trans_raw, n * 32 + half * 16 + i, isf32);
    const float tr_end = ldf(trans_raw, 32 + n, isf32);   // trans[END=1][n]

    float fvreg = (n == 0) ? 0.f : -10000.f;   // START=0; identical in all lanes
    float f0 = feats[0 * 32 + n], f1 = feats[1 * 32 + n];
    float f2 = feats[2 * 32 + n], f3 = feats[3 * 32 + n];

    auto step = [&](float& fslot, int ttv) {
        const float fcur = fslot;
        if (ttv + 4 < L_SEQ) fslot = feats[(long)(ttv + 4) * 32 + n];
        float best = -3.4e38f; int bp = 0;
        #pragma unroll
        for (int i = 0; i < 16; ++i) {
            const float cnd = tr[i] + __shfl(fvreg, half * 16 + i);
            if (cnd > best) { best = cnd; bp = half * 16 + i; }   // first max wins
        }
        const float ob = __shfl_xor(best, 32);
        const int  obp = __shfl_xor(bp, 32);
        if (ob > best || (ob == best && obp < bp)) { best = ob; bp = obp; }
        fvreg = best + fcur;
        if (half == 0) bptr[(long)ttv * 32 + n] = (u8)bp;
    };

    #pragma unroll 1
    for (int tt = 0; tt < L_SEQ; tt += 4) {
        step(f0, tt); step(f1, tt + 1); step(f2, tt + 2); step(f3, tt + 3);
    }

    float term = (half == 0) ? (fvreg + tr_end) : -3.4e38f;
    int   ti   = (half == 0) ? n : 1000;
    #pragma unroll
    for (int m = 1; m < 64; m <<= 1) {
        const float ov = __shfl_xor(term, m);
        const int   oi = __shfl_xor(ti, m);
        if (ov > term || (ov == term && oi < ti)) { term = ov; ti = oi; }
    }
    if (lane == 0) out[0] = term;
    __syncthreads();

    unsigned cur[32];
    #pragma unroll
    for (int ch = 0; ch < 32; ++ch) cur[ch] = (unsigned)ch;
    const int cbase = lane * 64;
    for (int s = 63; s >= 0; --s) {
        const u8* row = bptr + (long)(cbase + s) * 32;
        #pragma unroll
        for (int ch = 0; ch < 32; ++ch) cur[ch] = row[cur[ch]];
    }
    #pragma unroll
    for (int ch = 0; ch < 32; ++ch) mlds[lane * 32 + ch] = (u8)cur[ch];
    __syncthreads();

    if (lane == 0) {
        int tag = ti;
        for (int cc = 63; cc >= 0; --cc) { entry[cc] = (u8)tag; tag = mlds[cc * 32 + tag]; }
    }
    __syncthreads();

    {
        int tag = entry[lane];
        for (int s = 63; s >= 0; --s) {
            const int gidx = cbase + s;
            out[1 + gidx] = (float)tag;
            tag = bptr[(long)gidx * 32 + tag];
        }
    }
}

// ---------------------------------------------------------------------------
extern "C" void kernel_launch(void* const* d_in, const int* in_sizes, int n_in,
                              void* d_out, int out_size, void* d_ws, size_t ws_size,
                              hipStream_t stream)
{
    (void)in_sizes; (void)n_in; (void)out_size; (void)ws_size;
    const int* sent  = (const int*)d_in[0];
    const void* embed  = d_in[1];
    const void* w_ih_f = d_in[2];
    const void* w_hh_f = d_in[3];
    const void* b_ih_f = d_in[4];
    const void* b_hh_f = d_in[5];
    const void* w_ih_b = d_in[6];
    const void* w_hh_b = d_in[7];
    const void* b_ih_b = d_in[8];
    const void* b_hh_b = d_in[9];
    const void* w_out  = d_in[10];
    const void* b_out  = d_in[11];
    const void* h0     = d_in[12];
    const void* c0     = d_in[13];
    const void* trans  = d_in[14];

    char* ws = (char*)d_ws;
    float* xp_f  = (float*)(ws);                    // 32 MB (4096x2048 f32)
    float* xp_b  = (float*)(ws + (32ull << 20));    // 32 MB
    u64*   hsT_f = (u64*)(ws + (64ull << 20));      // 16 MB (4096x512 tagged u64)
    u64*   hsT_b = (u64*)(ws + (80ull << 20));      // 16 MB
    float* feats = (float*)(ws);                    // reuses xp_f (dead post-LSTM)
    u8*    bptr  = (u8*)(ws + (1ull << 20));        // 128 KB, also dead region

    k_xproj<<<dim3(256, 2), 256, 0, stream>>>(sent, embed,
        w_ih_f, b_ih_f, b_hh_f, w_ih_b, b_ih_b, b_hh_b, trans, xp_f, xp_b);
    k_lstm<<<256, 256, 0, stream>>>(w_hh_f, w_hh_b, h0, c0, trans, xp_f, xp_b, hsT_f, hsT_b);
    k_feats<<<512, 256, 0, stream>>>(hsT_f, hsT_b, w_out, b_out, trans, feats);
    k_viterbi<<<1, 64, 0, stream>>>(feats, trans, bptr, (float*)d_out);
}